// Round 2
// baseline (3422.771 us; speedup 1.0000x reference)
//
#include <hip/hip_runtime.h>
#include <hip/hip_bf16.h>
#include <stdint.h>

#define D_MODEL 1024
#define D_FF    4096
#define N_ZONES 8
#define TOPK    3
#define RH      256
#define BATCH   16
#define SEQ     2048
#define NPAIR   (BATCH * TOPK)   // 48 active (batch, expert) pairs, always exactly 3/batch

typedef __bf16 bf16;
typedef __bf16 bf16x8 __attribute__((ext_vector_type(8)));
typedef float  f32x4  __attribute__((ext_vector_type(4)));

// ---------------- helpers ----------------

__device__ __forceinline__ void gload16(const void* g, void* l) {
  // async global->LDS, 16B per lane; LDS dest is wave-uniform base + lane*16
  __builtin_amdgcn_global_load_lds((const __attribute__((address_space(1))) void*)g,
                                   (__attribute__((address_space(3))) void*)l,
                                   16, 0, 0);
}

__device__ __forceinline__ float gelu_tanh(float x) {
  // jax.nn.gelu(approximate=True): 0.5*x*(1+tanh(sqrt(2/pi)*(x+0.044715*x^3)))
  float inner = 0.7978845608028654f * (x + 0.044715f * x * x * x);
  float t = __expf(2.0f * inner);          // tanh(z) = 1 - 2/(e^{2z}+1)
  float th = 1.0f - 2.0f / (t + 1.0f);
  return 0.5f * x * (1.0f + th);
}

// ---------------- pooling ----------------

__global__ void pool_partial_kernel(const float* __restrict__ x, float* __restrict__ partial) {
  int sc = blockIdx.x;              // 8 chunks of 256 seq positions
  int b  = blockIdx.y;              // 16 batches
  int tid = threadIdx.x;
  const float* xp = x + ((size_t)b * SEQ + (size_t)sc * 256) * D_MODEL;
  for (int i = 0; i < D_MODEL / 256; ++i) {
    int d = tid + i * 256;
    float s = 0.f;
    for (int ss = 0; ss < 256; ++ss) s += xp[(size_t)ss * D_MODEL + d];
    partial[((size_t)sc * BATCH + b) * D_MODEL + d] = s;
  }
}

__global__ void pool_final_kernel(const float* __restrict__ partial, float* __restrict__ pooled) {
  int b = blockIdx.x;
  int tid = threadIdx.x;
  for (int i = 0; i < D_MODEL / 256; ++i) {
    int d = tid + i * 256;
    float s = 0.f;
    for (int sc = 0; sc < 8; ++sc) s += partial[((size_t)sc * BATCH + b) * D_MODEL + d];
    pooled[b * D_MODEL + d] = s * (1.0f / SEQ);
  }
}

// ---------------- router (1 block, trivial cost) ----------------

__global__ void router_kernel(const float* __restrict__ pooled,
                              const float* __restrict__ W1, const float* __restrict__ b1,
                              const float* __restrict__ W2, const float* __restrict__ b2,
                              int* __restrict__ route_e, float* __restrict__ route_w) {
  __shared__ float hls[RH];
  __shared__ float lg[N_ZONES];
  int tid = threadIdx.x;
  for (int b = 0; b < BATCH; ++b) {
    float acc = b1[tid];
    const float* pp = pooled + b * D_MODEL;
    for (int k = 0; k < D_MODEL; ++k) acc += pp[k] * W1[k * RH + tid];
    hls[tid] = tanhf(acc);
    __syncthreads();
    if (tid < N_ZONES) {
      float s = b2[tid];
      for (int j = 0; j < RH; ++j) s += hls[j] * W2[j * N_ZONES + tid];
      lg[tid] = s;
    }
    __syncthreads();
    if (tid == 0) {
      float m = lg[0];
      for (int e = 1; e < N_ZONES; ++e) m = fmaxf(m, lg[e]);
      float p[N_ZONES]; float sum = 0.f;
      for (int e = 0; e < N_ZONES; ++e) { p[e] = expf(lg[e] - m); sum += p[e]; }
      int used[N_ZONES] = {0};
      int idx[TOPK]; float tv[TOPK]; float tsum = 0.f;
      for (int r = 0; r < TOPK; ++r) {
        int best = 0; float bv = -1.f;
        for (int e = 0; e < N_ZONES; ++e)
          if (!used[e] && p[e] > bv) { bv = p[e]; best = e; }   // strict '>' = lowest index on tie (matches lax.top_k)
        used[best] = 1; idx[r] = best; tv[r] = bv / sum; tsum += bv / sum;
      }
      for (int r = 0; r < TOPK; ++r) {
        route_e[b * TOPK + r] = idx[r];
        route_w[b * TOPK + r] = tv[r] / tsum;   // renormalized top-k weight
      }
    }
    __syncthreads();
  }
}

// ---------------- one-time dtype conversion / transposes ----------------

__global__ void convert_x_kernel(const float* __restrict__ x, bf16* __restrict__ xb) {
  size_t i = ((size_t)blockIdx.x * blockDim.x + threadIdx.x) * 8;
  const float4* p = (const float4*)(x + i);
  float4 v0 = p[0], v1 = p[1];
  bf16x8 o;
  o[0] = (bf16)v0.x; o[1] = (bf16)v0.y; o[2] = (bf16)v0.z; o[3] = (bf16)v0.w;
  o[4] = (bf16)v1.x; o[5] = (bf16)v1.y; o[6] = (bf16)v1.z; o[7] = (bf16)v1.w;
  *(bf16x8*)(xb + i) = o;
}

// src: f32 [R][C] (per-expert stride R*C), dst: bf16 [C][R]
__global__ void transpose_kernel(const float* __restrict__ src, bf16* __restrict__ dst, int R, int C) {
  __shared__ float tile[64][65];
  int e = blockIdx.z;
  const float* s = src + (size_t)e * R * C;
  bf16* d = dst + (size_t)e * R * C;
  int r0 = blockIdx.y * 64, c0 = blockIdx.x * 64;
  int tc = threadIdx.x & 63, tr4 = threadIdx.x >> 6;
  for (int i = 0; i < 16; ++i) {
    int r = i * 4 + tr4;
    tile[r][tc] = s[(size_t)(r0 + r) * C + (c0 + tc)];
  }
  __syncthreads();
  for (int i = 0; i < 16; ++i) {
    int cc = i * 4 + tr4;
    d[(size_t)(c0 + cc) * R + (r0 + tc)] = (bf16)tile[tc][cc];
  }
}

// ---------------- GEMM1: h = gelu(xb @ Wa[e]) * w_r   (A=[M,K] rm, B^T=[N,K] rm) ----------------

__launch_bounds__(256)
__global__ void gemm1_kernel(const bf16* __restrict__ xb, const bf16* __restrict__ WaT,
                             const int* __restrict__ route_e, const float* __restrict__ route_w,
                             bf16* __restrict__ hbuf, int s_base, int SR) {
  __shared__ bf16 As[128 * 64];
  __shared__ bf16 Bs[128 * 64];
  const int pair = blockIdx.z;
  const int b = pair / TOPK;
  const int e = route_e[pair];
  const float wr = route_w[pair];
  const int m0 = blockIdx.y * 128;
  const int n0 = blockIdx.x * 128;
  const int tid = threadIdx.x;
  const int lane = tid & 63;
  const int wv = tid >> 6;
  const int wm = wv >> 1, wn = wv & 1;
  const int fr = lane & 15, fq = lane >> 4;
  const int crow = lane >> 3;            // row within 8-row staging chunk
  const int ckel = (lane & 7) * 8;       // k element offset within BK=64

  const bf16* Ab = xb  + ((size_t)b * SEQ + (size_t)(s_base + m0)) * D_MODEL;
  const bf16* Bb = WaT + ((size_t)e * D_FF + n0) * D_MODEL;

  f32x4 acc[4][4] = {};

  for (int kk = 0; kk < D_MODEL / 64; ++kk) {
    const int kofs = kk * 64;
#pragma unroll
    for (int c = 0; c < 4; ++c) {
      const int g = wv * 4 + c;
      const int row = g * 8 + crow;
      gload16(Ab + (size_t)row * D_MODEL + kofs + ckel, (void*)&As[g * 512]);
      gload16(Bb + (size_t)row * D_MODEL + kofs + ckel, (void*)&Bs[g * 512]);
    }
    __syncthreads();
#pragma unroll
    for (int kh = 0; kh < 2; ++kh) {
      bf16x8 af[4], bf_[4];
#pragma unroll
      for (int i = 0; i < 4; ++i) {
        af[i]  = *(const bf16x8*)&As[(wm * 64 + i * 16 + fr) * 64 + kh * 32 + fq * 8];
        bf_[i] = *(const bf16x8*)&Bs[(wn * 64 + i * 16 + fr) * 64 + kh * 32 + fq * 8];
      }
#pragma unroll
      for (int mi = 0; mi < 4; ++mi)
#pragma unroll
        for (int ni = 0; ni < 4; ++ni)
          acc[mi][ni] = __builtin_amdgcn_mfma_f32_16x16x32_bf16(af[mi], bf_[ni], acc[mi][ni], 0, 0, 0);
    }
    __syncthreads();
  }

  // epilogue: gelu, bake in routing weight, store bf16 h
  bf16* hout = hbuf + ((size_t)pair * SR + m0) * D_FF + n0;
#pragma unroll
  for (int mi = 0; mi < 4; ++mi) {
    const int row0 = wm * 64 + mi * 16 + fq * 4;
#pragma unroll
    for (int ni = 0; ni < 4; ++ni) {
      const int col = wn * 64 + ni * 16 + fr;
#pragma unroll
      for (int j = 0; j < 4; ++j) {
        float v = acc[mi][ni][j];
        hout[(size_t)(row0 + j) * D_FF + col] = (bf16)(gelu_tanh(v) * wr);
      }
    }
  }
}

// ---------------- GEMM2: out = x + sum_r h[b,r] @ Wb[e_r]   (w already baked into h) ----------------

__launch_bounds__(256)
__global__ void gemm2_kernel(const bf16* __restrict__ hbuf, const bf16* __restrict__ WbT,
                             const int* __restrict__ route_e,
                             const float* __restrict__ x, float* __restrict__ out,
                             int s_base, int SR) {
  __shared__ bf16 As[128 * 64];
  __shared__ bf16 Bs[128 * 64];
  const int b = blockIdx.z;
  const int m0 = blockIdx.y * 128;
  const int n0 = blockIdx.x * 128;   // output feature dim
  const int tid = threadIdx.x;
  const int lane = tid & 63;
  const int wv = tid >> 6;
  const int wm = wv >> 1, wn = wv & 1;
  const int fr = lane & 15, fq = lane >> 4;
  const int crow = lane >> 3;
  const int ckel = (lane & 7) * 8;

  f32x4 acc[4][4] = {};

  // outer loop over the 3 routed ranks; inner over K=D_FF in 64-steps.
  // expert pointer hoisted per-rank (FIX: round-0 bug always used expert 0's Wb)
  for (int r = 0; r < TOPK; ++r) {
    const int e = route_e[b * TOPK + r];
    const bf16* Ab = hbuf + ((size_t)(b * TOPK + r) * SR + m0) * D_FF;
    const bf16* Bb = WbT + ((size_t)e * D_MODEL + n0) * D_FF;

    for (int kk = 0; kk < D_FF / 64; ++kk) {
      const int kofs = kk * 64;
#pragma unroll
      for (int c = 0; c < 4; ++c) {
        const int g = wv * 4 + c;
        const int row = g * 8 + crow;
        gload16(Ab + (size_t)row * D_FF + kofs + ckel, (void*)&As[g * 512]);
        gload16(Bb + (size_t)row * D_FF + kofs + ckel, (void*)&Bs[g * 512]);
      }
      __syncthreads();
#pragma unroll
      for (int kh = 0; kh < 2; ++kh) {
        bf16x8 af[4], bf_[4];
#pragma unroll
        for (int i = 0; i < 4; ++i) {
          af[i]  = *(const bf16x8*)&As[(wm * 64 + i * 16 + fr) * 64 + kh * 32 + fq * 8];
          bf_[i] = *(const bf16x8*)&Bs[(wn * 64 + i * 16 + fr) * 64 + kh * 32 + fq * 8];
        }
#pragma unroll
        for (int mi = 0; mi < 4; ++mi)
#pragma unroll
          for (int ni = 0; ni < 4; ++ni)
            acc[mi][ni] = __builtin_amdgcn_mfma_f32_16x16x32_bf16(af[mi], bf_[ni], acc[mi][ni], 0, 0, 0);
      }
      __syncthreads();
    }
  }

  // epilogue: residual add, f32 out
  const size_t obase = ((size_t)b * SEQ + (size_t)(s_base + m0)) * D_MODEL + n0;
#pragma unroll
  for (int mi = 0; mi < 4; ++mi) {
    const int row0 = wm * 64 + mi * 16 + fq * 4;
#pragma unroll
    for (int ni = 0; ni < 4; ++ni) {
      const int col = wn * 64 + ni * 16 + fr;
#pragma unroll
      for (int j = 0; j < 4; ++j) {
        size_t idx = obase + (size_t)(row0 + j) * D_MODEL + col;
        out[idx] = x[idx] + acc[mi][ni][j];
      }
    }
  }
}

// ---------------- sentinel (ws too small — encodes ws_size in MB into absmax) ----------------

__global__ void fail_kernel(float* out, float v) {
  if (threadIdx.x < 64) out[threadIdx.x] = v;
}

// ---------------- host ----------------

extern "C" void kernel_launch(void* const* d_in, const int* in_sizes, int n_in,
                              void* d_out, int out_size, void* d_ws, size_t ws_size,
                              hipStream_t stream) {
  const float* x  = (const float*)d_in[0];
  const float* W1 = (const float*)d_in[1];
  const float* b1 = (const float*)d_in[2];
  const float* W2 = (const float*)d_in[3];
  const float* b2 = (const float*)d_in[4];
  const float* Wa = (const float*)d_in[5];
  const float* Wb = (const float*)d_in[6];
  float* out = (float*)d_out;

  char* ws = (char*)d_ws;
  size_t off = 0;
  auto walloc = [&](size_t bytes) -> void* {
    void* p = ws + off;
    off += (bytes + 255) & ~(size_t)255;
    return p;
  };

  float* partial = (float*)walloc((size_t)8 * BATCH * D_MODEL * 4);
  float* pooled  = (float*)walloc((size_t)BATCH * D_MODEL * 4);
  int*   route_e = (int*)walloc(NPAIR * 4);
  float* route_w = (float*)walloc(NPAIR * 4);
  bf16*  xb      = (bf16*)walloc((size_t)BATCH * SEQ * D_MODEL * 2);
  bf16*  WaT     = (bf16*)walloc((size_t)N_ZONES * D_MODEL * D_FF * 2);
  bf16*  WbT     = (bf16*)walloc((size_t)N_ZONES * D_MODEL * D_FF * 2);
  size_t fixed = off;

  int SR = 0;
  const int cands[3] = {512, 256, 128};   // prefer 512: h slice (192MB) ~fits L3
  for (int ci = 0; ci < 3; ++ci) {
    size_t need = fixed + (size_t)NPAIR * cands[ci] * D_FF * 2 + 1024;
    if (need <= ws_size) { SR = cands[ci]; break; }
  }
  if (SR == 0) {
    fail_kernel<<<1, 64, 0, stream>>>(out, 1.0e6f + (float)(ws_size >> 20));
    return;
  }
  bf16* hbuf = (bf16*)walloc((size_t)NPAIR * SR * D_FF * 2);

  // router path
  pool_partial_kernel<<<dim3(8, BATCH), 256, 0, stream>>>(x, partial);
  pool_final_kernel<<<BATCH, 256, 0, stream>>>(partial, pooled);
  router_kernel<<<1, RH, 0, stream>>>(pooled, W1, b1, W2, b2, route_e, route_w);

  // one-time conversions
  convert_x_kernel<<<(BATCH * SEQ * D_MODEL) / (256 * 8), 256, 0, stream>>>(x, xb);
  transpose_kernel<<<dim3(D_FF / 64, D_MODEL / 64, N_ZONES), 256, 0, stream>>>(Wa, WaT, D_MODEL, D_FF);
  transpose_kernel<<<dim3(D_MODEL / 64, D_FF / 64, N_ZONES), 256, 0, stream>>>(Wb, WbT, D_FF, D_MODEL);

  // sliced grouped-GEMM pipeline
  const int NS = SEQ / SR;
  for (int sl = 0; sl < NS; ++sl) {
    gemm1_kernel<<<dim3(D_FF / 128, SR / 128, NPAIR), 256, 0, stream>>>(
        xb, WaT, route_e, route_w, hbuf, sl * SR, SR);
    gemm2_kernel<<<dim3(D_MODEL / 128, SR / 128, BATCH), 256, 0, stream>>>(
        hbuf, WbT, route_e, x, out, sl * SR, SR);
  }
}

// Round 3
// 2993.712 us; speedup vs baseline: 1.1433x; 1.1433x over previous
//
#include <hip/hip_runtime.h>
#include <hip/hip_bf16.h>
#include <stdint.h>

#define D_MODEL 1024
#define D_FF    4096
#define N_ZONES 8
#define TOPK    3
#define RH      256
#define BATCH   16
#define SEQ     2048
#define NPAIR   (BATCH * TOPK)   // 48 active (batch, expert) pairs, always exactly 3/batch

typedef __bf16 bf16;
typedef __bf16 bf16x8 __attribute__((ext_vector_type(8)));
typedef float  f32x4  __attribute__((ext_vector_type(4)));

// ---------------- helpers ----------------

__device__ __forceinline__ void gload16(const void* g, void* l) {
  // async global->LDS, 16B per lane; LDS dest is wave-uniform base + lane*16
  __builtin_amdgcn_global_load_lds((const __attribute__((address_space(1))) void*)g,
                                   (__attribute__((address_space(3))) void*)l,
                                   16, 0, 0);
}

__device__ __forceinline__ float gelu_tanh(float x) {
  // jax.nn.gelu(approximate=True): 0.5*x*(1+tanh(sqrt(2/pi)*(x+0.044715*x^3)))
  float inner = 0.7978845608028654f * (x + 0.044715f * x * x * x);
  float t = __expf(2.0f * inner);          // tanh(z) = 1 - 2/(e^{2z}+1)
  float th = 1.0f - 2.0f / (t + 1.0f);
  return 0.5f * x * (1.0f + th);
}

// ---------------- pooling ----------------

__global__ void pool_partial_kernel(const float* __restrict__ x, float* __restrict__ partial) {
  int sc = blockIdx.x;              // 8 chunks of 256 seq positions
  int b  = blockIdx.y;              // 16 batches
  int tid = threadIdx.x;
  const float* xp = x + ((size_t)b * SEQ + (size_t)sc * 256) * D_MODEL;
  for (int i = 0; i < D_MODEL / 256; ++i) {
    int d = tid + i * 256;
    float s = 0.f;
    for (int ss = 0; ss < 256; ++ss) s += xp[(size_t)ss * D_MODEL + d];
    partial[((size_t)sc * BATCH + b) * D_MODEL + d] = s;
  }
}

__global__ void pool_final_kernel(const float* __restrict__ partial, float* __restrict__ pooled) {
  int b = blockIdx.x;
  int tid = threadIdx.x;
  for (int i = 0; i < D_MODEL / 256; ++i) {
    int d = tid + i * 256;
    float s = 0.f;
    for (int sc = 0; sc < 8; ++sc) s += partial[((size_t)sc * BATCH + b) * D_MODEL + d];
    pooled[b * D_MODEL + d] = s * (1.0f / SEQ);
  }
}

// ---------------- router: one block per batch, latency hidden via unroll ----------------

__global__ void router_kernel(const float* __restrict__ pooled,
                              const float* __restrict__ W1, const float* __restrict__ b1,
                              const float* __restrict__ W2, const float* __restrict__ b2,
                              int* __restrict__ route_e, float* __restrict__ route_w) {
  __shared__ float pld[D_MODEL];
  __shared__ float hls[RH];
  __shared__ float lg[N_ZONES];
  const int b = blockIdx.x;
  const int j = threadIdx.x;

  // stage pooled row into LDS (broadcast-friendly reads in the dot loop)
  for (int i = 0; i < D_MODEL / RH; ++i) pld[j + i * RH] = pooled[b * D_MODEL + j + i * RH];
  __syncthreads();

  float acc = b1[j];
#pragma unroll 8
  for (int k = 0; k < D_MODEL; ++k) acc += pld[k] * W1[k * RH + j];
  hls[j] = tanhf(acc);
  __syncthreads();

  if (j < N_ZONES) {
    float s = b2[j];
    for (int t = 0; t < RH; ++t) s += hls[t] * W2[t * N_ZONES + j];
    lg[j] = s;
  }
  __syncthreads();

  if (j == 0) {
    float m = lg[0];
    for (int e = 1; e < N_ZONES; ++e) m = fmaxf(m, lg[e]);
    float p[N_ZONES]; float sum = 0.f;
    for (int e = 0; e < N_ZONES; ++e) { p[e] = expf(lg[e] - m); sum += p[e]; }
    int used[N_ZONES] = {0};
    int idx[TOPK]; float tv[TOPK]; float tsum = 0.f;
    for (int r = 0; r < TOPK; ++r) {
      int best = 0; float bv = -1.f;
      for (int e = 0; e < N_ZONES; ++e)
        if (!used[e] && p[e] > bv) { bv = p[e]; best = e; }   // strict '>' = lowest index on tie (matches lax.top_k)
      used[best] = 1; idx[r] = best; tv[r] = bv / sum; tsum += bv / sum;
    }
    for (int r = 0; r < TOPK; ++r) {
      route_e[b * TOPK + r] = idx[r];
      route_w[b * TOPK + r] = tv[r] / tsum;   // renormalized top-k weight
    }
  }
}

// ---------------- one-time dtype conversion / transposes ----------------

__global__ void convert_x_kernel(const float* __restrict__ x, bf16* __restrict__ xb) {
  size_t i = ((size_t)blockIdx.x * blockDim.x + threadIdx.x) * 8;
  const float4* p = (const float4*)(x + i);
  float4 v0 = p[0], v1 = p[1];
  bf16x8 o;
  o[0] = (bf16)v0.x; o[1] = (bf16)v0.y; o[2] = (bf16)v0.z; o[3] = (bf16)v0.w;
  o[4] = (bf16)v1.x; o[5] = (bf16)v1.y; o[6] = (bf16)v1.z; o[7] = (bf16)v1.w;
  *(bf16x8*)(xb + i) = o;
}

// src: f32 [R][C] (per-expert stride R*C), dst: bf16 [C][R]
__global__ void transpose_kernel(const float* __restrict__ src, bf16* __restrict__ dst, int R, int C) {
  __shared__ float tile[64][65];
  int e = blockIdx.z;
  const float* s = src + (size_t)e * R * C;
  bf16* d = dst + (size_t)e * R * C;
  int r0 = blockIdx.y * 64, c0 = blockIdx.x * 64;
  int tc = threadIdx.x & 63, tr4 = threadIdx.x >> 6;
  for (int i = 0; i < 16; ++i) {
    int r = i * 4 + tr4;
    tile[r][tc] = s[(size_t)(r0 + r) * C + (c0 + tc)];
  }
  __syncthreads();
  for (int i = 0; i < 16; ++i) {
    int cc = i * 4 + tr4;
    d[(size_t)(c0 + cc) * R + (r0 + tc)] = (bf16)tile[tc][cc];
  }
}

// ---------------- GEMM1: h = gelu(xb @ Wa[e]) * w_r   (A=[M,K] rm, B^T=[N,K] rm) ----------------

__launch_bounds__(256)
__global__ void gemm1_kernel(const bf16* __restrict__ xb, const bf16* __restrict__ WaT,
                             const int* __restrict__ route_e, const float* __restrict__ route_w,
                             bf16* __restrict__ hbuf, int s_base, int SR) {
  __shared__ bf16 As[128 * 64];
  __shared__ bf16 Bs[128 * 64];
  const int pair = blockIdx.z;
  const int b = pair / TOPK;
  const int e = route_e[pair];
  const float wr = route_w[pair];
  const int m0 = blockIdx.y * 128;
  const int n0 = blockIdx.x * 128;
  const int tid = threadIdx.x;
  const int lane = tid & 63;
  const int wv = tid >> 6;
  const int wm = wv >> 1, wn = wv & 1;
  const int fr = lane & 15, fq = lane >> 4;
  const int crow = lane >> 3;            // row within 8-row staging chunk
  const int ckel = (lane & 7) * 8;       // k element offset within BK=64

  const bf16* Ab = xb  + ((size_t)b * SEQ + (size_t)(s_base + m0)) * D_MODEL;
  const bf16* Bb = WaT + ((size_t)e * D_FF + n0) * D_MODEL;

  f32x4 acc[4][4] = {};

  for (int kk = 0; kk < D_MODEL / 64; ++kk) {
    const int kofs = kk * 64;
#pragma unroll
    for (int c = 0; c < 4; ++c) {
      const int g = wv * 4 + c;
      const int row = g * 8 + crow;
      gload16(Ab + (size_t)row * D_MODEL + kofs + ckel, (void*)&As[g * 512]);
      gload16(Bb + (size_t)row * D_MODEL + kofs + ckel, (void*)&Bs[g * 512]);
    }
    __syncthreads();
#pragma unroll
    for (int kh = 0; kh < 2; ++kh) {
      bf16x8 af[4], bf_[4];
#pragma unroll
      for (int i = 0; i < 4; ++i) {
        af[i]  = *(const bf16x8*)&As[(wm * 64 + i * 16 + fr) * 64 + kh * 32 + fq * 8];
        bf_[i] = *(const bf16x8*)&Bs[(wn * 64 + i * 16 + fr) * 64 + kh * 32 + fq * 8];
      }
#pragma unroll
      for (int mi = 0; mi < 4; ++mi)
#pragma unroll
        for (int ni = 0; ni < 4; ++ni)
          acc[mi][ni] = __builtin_amdgcn_mfma_f32_16x16x32_bf16(af[mi], bf_[ni], acc[mi][ni], 0, 0, 0);
    }
    __syncthreads();
  }

  // epilogue: gelu, bake in routing weight, store bf16 h
  bf16* hout = hbuf + ((size_t)pair * SR + m0) * D_FF + n0;
#pragma unroll
  for (int mi = 0; mi < 4; ++mi) {
    const int row0 = wm * 64 + mi * 16 + fq * 4;
#pragma unroll
    for (int ni = 0; ni < 4; ++ni) {
      const int col = wn * 64 + ni * 16 + fr;
#pragma unroll
      for (int j = 0; j < 4; ++j) {
        float v = acc[mi][ni][j];
        hout[(size_t)(row0 + j) * D_FF + col] = (bf16)(gelu_tanh(v) * wr);
      }
    }
  }
}

// ---------------- GEMM2: out = x + sum_r h[b,r] @ Wb[e_r]   (w already baked into h) ----------------

__launch_bounds__(256)
__global__ void gemm2_kernel(const bf16* __restrict__ hbuf, const bf16* __restrict__ WbT,
                             const int* __restrict__ route_e,
                             const float* __restrict__ x, float* __restrict__ out,
                             int s_base, int SR) {
  __shared__ bf16 As[128 * 64];
  __shared__ bf16 Bs[128 * 64];
  const int b = blockIdx.z;
  const int m0 = blockIdx.y * 128;
  const int n0 = blockIdx.x * 128;   // output feature dim
  const int tid = threadIdx.x;
  const int lane = tid & 63;
  const int wv = tid >> 6;
  const int wm = wv >> 1, wn = wv & 1;
  const int fr = lane & 15, fq = lane >> 4;
  const int crow = lane >> 3;
  const int ckel = (lane & 7) * 8;

  f32x4 acc[4][4] = {};

  // outer loop over the 3 routed ranks; inner over K=D_FF in 64-steps.
  for (int r = 0; r < TOPK; ++r) {
    const int e = route_e[b * TOPK + r];
    const bf16* Ab = hbuf + ((size_t)(b * TOPK + r) * SR + m0) * D_FF;
    const bf16* Bb = WbT + ((size_t)e * D_MODEL + n0) * D_FF;

    for (int kk = 0; kk < D_FF / 64; ++kk) {
      const int kofs = kk * 64;
#pragma unroll
      for (int c = 0; c < 4; ++c) {
        const int g = wv * 4 + c;
        const int row = g * 8 + crow;
        gload16(Ab + (size_t)row * D_FF + kofs + ckel, (void*)&As[g * 512]);
        gload16(Bb + (size_t)row * D_FF + kofs + ckel, (void*)&Bs[g * 512]);
      }
      __syncthreads();
#pragma unroll
      for (int kh = 0; kh < 2; ++kh) {
        bf16x8 af[4], bf_[4];
#pragma unroll
        for (int i = 0; i < 4; ++i) {
          af[i]  = *(const bf16x8*)&As[(wm * 64 + i * 16 + fr) * 64 + kh * 32 + fq * 8];
          bf_[i] = *(const bf16x8*)&Bs[(wn * 64 + i * 16 + fr) * 64 + kh * 32 + fq * 8];
        }
#pragma unroll
        for (int mi = 0; mi < 4; ++mi)
#pragma unroll
          for (int ni = 0; ni < 4; ++ni)
            acc[mi][ni] = __builtin_amdgcn_mfma_f32_16x16x32_bf16(af[mi], bf_[ni], acc[mi][ni], 0, 0, 0);
      }
      __syncthreads();
    }
  }

  // epilogue: residual add, f32 out
  const size_t obase = ((size_t)b * SEQ + (size_t)(s_base + m0)) * D_MODEL + n0;
#pragma unroll
  for (int mi = 0; mi < 4; ++mi) {
    const int row0 = wm * 64 + mi * 16 + fq * 4;
#pragma unroll
    for (int ni = 0; ni < 4; ++ni) {
      const int col = wn * 64 + ni * 16 + fr;
#pragma unroll
      for (int j = 0; j < 4; ++j) {
        size_t idx = obase + (size_t)(row0 + j) * D_MODEL + col;
        out[idx] = x[idx] + acc[mi][ni][j];
      }
    }
  }
}

// ---------------- sentinel (ws too small — encodes ws_size in MB into absmax) ----------------

__global__ void fail_kernel(float* out, float v) {
  if (threadIdx.x < 64) out[threadIdx.x] = v;
}

// ---------------- host ----------------

extern "C" void kernel_launch(void* const* d_in, const int* in_sizes, int n_in,
                              void* d_out, int out_size, void* d_ws, size_t ws_size,
                              hipStream_t stream) {
  const float* x  = (const float*)d_in[0];
  const float* W1 = (const float*)d_in[1];
  const float* b1 = (const float*)d_in[2];
  const float* W2 = (const float*)d_in[3];
  const float* b2 = (const float*)d_in[4];
  const float* Wa = (const float*)d_in[5];
  const float* Wb = (const float*)d_in[6];
  float* out = (float*)d_out;

  char* ws = (char*)d_ws;
  size_t off = 0;
  auto walloc = [&](size_t bytes) -> void* {
    void* p = ws + off;
    off += (bytes + 255) & ~(size_t)255;
    return p;
  };

  float* partial = (float*)walloc((size_t)8 * BATCH * D_MODEL * 4);
  float* pooled  = (float*)walloc((size_t)BATCH * D_MODEL * 4);
  int*   route_e = (int*)walloc(NPAIR * 4);
  float* route_w = (float*)walloc(NPAIR * 4);
  bf16*  xb      = (bf16*)walloc((size_t)BATCH * SEQ * D_MODEL * 2);
  bf16*  WaT     = (bf16*)walloc((size_t)N_ZONES * D_MODEL * D_FF * 2);
  bf16*  WbT     = (bf16*)walloc((size_t)N_ZONES * D_MODEL * D_FF * 2);
  size_t fixed = off;

  int SR = 0;
  const int cands[3] = {512, 256, 128};   // prefer 512: h slice (192MB) ~fits L3
  for (int ci = 0; ci < 3; ++ci) {
    size_t need = fixed + (size_t)NPAIR * cands[ci] * D_FF * 2 + 1024;
    if (need <= ws_size) { SR = cands[ci]; break; }
  }
  if (SR == 0) {
    fail_kernel<<<1, 64, 0, stream>>>(out, 1.0e6f + (float)(ws_size >> 20));
    return;
  }
  bf16* hbuf = (bf16*)walloc((size_t)NPAIR * SR * D_FF * 2);

  // router path
  pool_partial_kernel<<<dim3(8, BATCH), 256, 0, stream>>>(x, partial);
  pool_final_kernel<<<BATCH, 256, 0, stream>>>(partial, pooled);
  router_kernel<<<BATCH, RH, 0, stream>>>(pooled, W1, b1, W2, b2, route_e, route_w);

  // one-time conversions
  convert_x_kernel<<<(BATCH * SEQ * D_MODEL) / (256 * 8), 256, 0, stream>>>(x, xb);
  transpose_kernel<<<dim3(D_FF / 64, D_MODEL / 64, N_ZONES), 256, 0, stream>>>(Wa, WaT, D_MODEL, D_FF);
  transpose_kernel<<<dim3(D_MODEL / 64, D_FF / 64, N_ZONES), 256, 0, stream>>>(Wb, WbT, D_FF, D_MODEL);

  // sliced grouped-GEMM pipeline
  const int NS = SEQ / SR;
  for (int sl = 0; sl < NS; ++sl) {
    gemm1_kernel<<<dim3(D_FF / 128, SR / 128, NPAIR), 256, 0, stream>>>(
        xb, WaT, route_e, route_w, hbuf, sl * SR, SR);
    gemm2_kernel<<<dim3(D_MODEL / 128, SR / 128, BATCH), 256, 0, stream>>>(
        hbuf, WbT, route_e, x, out, sl * SR, SR);
  }
}

// Round 4
// 2846.489 us; speedup vs baseline: 1.2025x; 1.0517x over previous
//
#include <hip/hip_runtime.h>
#include <hip/hip_bf16.h>
#include <stdint.h>

#define D_MODEL 1024
#define D_FF    4096
#define N_ZONES 8
#define TOPK    3
#define RH      256
#define BATCH   16
#define SEQ     2048
#define NPAIR   (BATCH * TOPK)

typedef __bf16 bf16;
typedef __bf16 bf16x8 __attribute__((ext_vector_type(8)));
typedef float  f32x4  __attribute__((ext_vector_type(4)));

// ---------------- helpers ----------------

__device__ __forceinline__ void gload16(const void* g, void* l) {
  __builtin_amdgcn_global_load_lds((const __attribute__((address_space(1))) void*)g,
                                   (__attribute__((address_space(3))) void*)l,
                                   16, 0, 0);
}

__device__ __forceinline__ float gelu_tanh(float x) {
  float inner = 0.7978845608028654f * (x + 0.044715f * x * x * x);
  float t = __expf(2.0f * inner);
  float th = 1.0f - 2.0f / (t + 1.0f);
  return 0.5f * x * (1.0f + th);
}

// ---------------- pooling ----------------

__global__ void pool_partial_kernel(const float* __restrict__ x, float* __restrict__ partial) {
  int sc = blockIdx.x;
  int b  = blockIdx.y;
  int tid = threadIdx.x;
  const float* xp = x + ((size_t)b * SEQ + (size_t)sc * 256) * D_MODEL;
  for (int i = 0; i < D_MODEL / 256; ++i) {
    int d = tid + i * 256;
    float s = 0.f;
    for (int ss = 0; ss < 256; ++ss) s += xp[(size_t)ss * D_MODEL + d];
    partial[((size_t)sc * BATCH + b) * D_MODEL + d] = s;
  }
}

__global__ void pool_final_kernel(const float* __restrict__ partial, float* __restrict__ pooled) {
  int b = blockIdx.x;
  int tid = threadIdx.x;
  for (int i = 0; i < D_MODEL / 256; ++i) {
    int d = tid + i * 256;
    float s = 0.f;
    for (int sc = 0; sc < 8; ++sc) s += partial[((size_t)sc * BATCH + b) * D_MODEL + d];
    pooled[b * D_MODEL + d] = s * (1.0f / SEQ);
  }
}

// ---------------- router ----------------

__global__ void router_kernel(const float* __restrict__ pooled,
                              const float* __restrict__ W1, const float* __restrict__ b1,
                              const float* __restrict__ W2, const float* __restrict__ b2,
                              int* __restrict__ route_e, float* __restrict__ route_w) {
  __shared__ float pld[D_MODEL];
  __shared__ float hls[RH];
  __shared__ float lg[N_ZONES];
  const int b = blockIdx.x;
  const int j = threadIdx.x;

  for (int i = 0; i < D_MODEL / RH; ++i) pld[j + i * RH] = pooled[b * D_MODEL + j + i * RH];
  __syncthreads();

  float acc = b1[j];
#pragma unroll 8
  for (int k = 0; k < D_MODEL; ++k) acc += pld[k] * W1[k * RH + j];
  hls[j] = tanhf(acc);
  __syncthreads();

  if (j < N_ZONES) {
    float s = b2[j];
    for (int t = 0; t < RH; ++t) s += hls[t] * W2[t * N_ZONES + j];
    lg[j] = s;
  }
  __syncthreads();

  if (j == 0) {
    float m = lg[0];
    for (int e = 1; e < N_ZONES; ++e) m = fmaxf(m, lg[e]);
    float p[N_ZONES]; float sum = 0.f;
    for (int e = 0; e < N_ZONES; ++e) { p[e] = expf(lg[e] - m); sum += p[e]; }
    int used[N_ZONES] = {0};
    int idx[TOPK]; float tv[TOPK]; float tsum = 0.f;
    for (int r = 0; r < TOPK; ++r) {
      int best = 0; float bv = -1.f;
      for (int e = 0; e < N_ZONES; ++e)
        if (!used[e] && p[e] > bv) { bv = p[e]; best = e; }
      used[best] = 1; idx[r] = best; tv[r] = bv / sum; tsum += bv / sum;
    }
    for (int r = 0; r < TOPK; ++r) {
      route_e[b * TOPK + r] = idx[r];
      route_w[b * TOPK + r] = tv[r] / tsum;
    }
  }
}

// ---------------- conversions ----------------

__global__ void convert_x_kernel(const float* __restrict__ x, bf16* __restrict__ xb) {
  size_t i = ((size_t)blockIdx.x * blockDim.x + threadIdx.x) * 8;
  const float4* p = (const float4*)(x + i);
  float4 v0 = p[0], v1 = p[1];
  bf16x8 o;
  o[0] = (bf16)v0.x; o[1] = (bf16)v0.y; o[2] = (bf16)v0.z; o[3] = (bf16)v0.w;
  o[4] = (bf16)v1.x; o[5] = (bf16)v1.y; o[6] = (bf16)v1.z; o[7] = (bf16)v1.w;
  *(bf16x8*)(xb + i) = o;
}

__global__ void transpose_kernel(const float* __restrict__ src, bf16* __restrict__ dst, int R, int C) {
  __shared__ float tile[64][65];
  int e = blockIdx.z;
  const float* s = src + (size_t)e * R * C;
  bf16* d = dst + (size_t)e * R * C;
  int r0 = blockIdx.y * 64, c0 = blockIdx.x * 64;
  int tc = threadIdx.x & 63, tr4 = threadIdx.x >> 6;
  for (int i = 0; i < 16; ++i) {
    int r = i * 4 + tr4;
    tile[r][tc] = s[(size_t)(r0 + r) * C + (c0 + tc)];
  }
  __syncthreads();
  for (int i = 0; i < 16; ++i) {
    int cc = i * 4 + tr4;
    d[(size_t)(c0 + cc) * R + (r0 + tc)] = (bf16)tile[tc][cc];
  }
}

// ---------------- 256x256 8-phase GEMM bodies ----------------
// LDS half-tile: [256 rows][32 k-cols] bf16 (16KB). Ring: [2 dbuf][2 khalf] per operand.
// Stage: inverse-swizzled global source, linear LDS dest (rule 21).
// Read: slot ^= (row>>1)&3 on 16B slots -> ~2-way bank conflicts.
// Per-phase: stage 1 half-tile; vmcnt(6); s_barrier; ds_read frags; 16 MFMA (setprio-wrapped).

#define STAGE1(gb, ld, colb, ldsb)                                            \
  { const bf16* _s = (gb) + (size_t)(w * 16 + srow) * (ld) + (colb) + swz;    \
    gload16(_s, (bf16*)(ldsb) + w * 512);                                     \
    gload16(_s + (size_t)128 * (ld), (bf16*)(ldsb) + 4096 + w * 512); }

#define SYNC6()                                                               \
    asm volatile("s_waitcnt vmcnt(6)" ::: "memory");                          \
    __builtin_amdgcn_s_barrier();                                             \
    __builtin_amdgcn_sched_barrier(0);

#define LOADB(kh_)                                                            \
    { const bf16* Bh = &Bs[(buf * 2 + (kh_)) * 8192] + (wn * 64 + fr) * 32 + swr; \
      _Pragma("unroll")                                                       \
      for (int ni = 0; ni < 4; ++ni) bfr[ni] = *(const bf16x8*)(Bh + ni * 512); }

#define MFMA16(kh_, mh_)                                                      \
    { const bf16* Ah = &As[(buf * 2 + (kh_)) * 8192] + (wm * 128 + (mh_) * 64 + fr) * 32 + swr; \
      bf16x8 af[4];                                                           \
      _Pragma("unroll")                                                       \
      for (int mi = 0; mi < 4; ++mi) af[mi] = *(const bf16x8*)(Ah + mi * 512); \
      __builtin_amdgcn_s_setprio(1);                                          \
      _Pragma("unroll")                                                       \
      for (int mi = 0; mi < 4; ++mi)                                          \
        _Pragma("unroll")                                                     \
        for (int ni = 0; ni < 4; ++ni)                                        \
          acc[(mh_) * 4 + mi][ni] = __builtin_amdgcn_mfma_f32_16x16x32_bf16(af[mi], bfr[ni], acc[(mh_) * 4 + mi][ni], 0, 0, 0); \
      __builtin_amdgcn_s_setprio(0); }

// GEMM1: h = gelu(xb @ Wa[e]) * w_r ; A=[SR,1024] rm, B^T=[4096,1024] rm
__launch_bounds__(512, 2)
__global__ void gemm1_kernel(const bf16* __restrict__ xb, const bf16* __restrict__ WaT,
                             const int* __restrict__ route_e, const float* __restrict__ route_w,
                             bf16* __restrict__ hbuf, int s_base, int SR) {
  __shared__ bf16 As[2 * 2 * 256 * 32];
  __shared__ bf16 Bs[2 * 2 * 256 * 32];
  const int pair = blockIdx.z;
  const int b = pair / TOPK;
  const int e = route_e[pair];
  const float wr = route_w[pair];
  const int m0 = blockIdx.y * 256;
  const int n0 = blockIdx.x * 256;
  const int tid = threadIdx.x;
  const int lane = tid & 63;
  const int w = tid >> 6;
  const int wm = w >> 2, wn = w & 3;
  const int fr = lane & 15, fq = lane >> 4;
  const int swz = (((lane & 3) ^ ((lane >> 3) & 3)) * 8);
  const int swr = ((fq ^ ((fr >> 1) & 3)) * 8);
  const int srow = lane >> 2;

  const bf16* Ag = xb  + ((size_t)b * SEQ + (size_t)(s_base + m0)) * D_MODEL;
  const bf16* Bg = WaT + ((size_t)e * D_FF + n0) * D_MODEL;

  f32x4 acc[8][4] = {};
  bf16x8 bfr[4];

  // prologue: tile 0 (both k-halves, A and B) into buf 0
  STAGE1(Ag, D_MODEL, 0,  &As[0]);
  STAGE1(Bg, D_MODEL, 0,  &Bs[0]);
  STAGE1(Ag, D_MODEL, 32, &As[8192]);
  STAGE1(Bg, D_MODEL, 32, &Bs[8192]);

  const int NT = D_MODEL / 64;  // 16
  for (int t = 0; t < NT; ++t) {
    const int buf = t & 1, nbuf = buf ^ 1;
    const int gn = (t + 1 < NT) ? t + 1 : NT - 1;  // clamped dummy at tail keeps vmcnt window moving
    const int cb = gn * 64;
    STAGE1(Ag, D_MODEL, cb,      &As[(nbuf * 2 + 0) * 8192]);  SYNC6(); LOADB(0); MFMA16(0, 0);
    STAGE1(Bg, D_MODEL, cb,      &Bs[(nbuf * 2 + 0) * 8192]);  SYNC6();           MFMA16(0, 1);
    STAGE1(Ag, D_MODEL, cb + 32, &As[(nbuf * 2 + 1) * 8192]);  SYNC6(); LOADB(1); MFMA16(1, 0);
    STAGE1(Bg, D_MODEL, cb + 32, &Bs[(nbuf * 2 + 1) * 8192]);  SYNC6();           MFMA16(1, 1);
  }

  // epilogue: gelu * wr, bf16 store
  bf16* hout = hbuf + ((size_t)pair * SR + m0 + wm * 128) * D_FF + n0 + wn * 64;
#pragma unroll
  for (int MI = 0; MI < 8; ++MI)
#pragma unroll
    for (int ni = 0; ni < 4; ++ni)
#pragma unroll
      for (int j = 0; j < 4; ++j) {
        float v = acc[MI][ni][j];
        hout[(size_t)(MI * 16 + fq * 4 + j) * D_FF + ni * 16 + fr] = (bf16)(gelu_tanh(v) * wr);
      }
}

// GEMM2: out = x + sum_r h[b,r] @ Wb[e_r] ; A=[SR,4096]x3 rm, B^T=[1024,4096] rm per expert
__launch_bounds__(512, 2)
__global__ void gemm2_kernel(const bf16* __restrict__ hbuf, const bf16* __restrict__ WbT,
                             const int* __restrict__ route_e,
                             const float* __restrict__ x, float* __restrict__ out,
                             int s_base, int SR) {
  __shared__ bf16 As[2 * 2 * 256 * 32];
  __shared__ bf16 Bs[2 * 2 * 256 * 32];
  const int b = blockIdx.z;
  const int m0 = blockIdx.y * 256;
  const int n0 = blockIdx.x * 256;
  const int tid = threadIdx.x;
  const int lane = tid & 63;
  const int w = tid >> 6;
  const int wm = w >> 2, wn = w & 3;
  const int fr = lane & 15, fq = lane >> 4;
  const int swz = (((lane & 3) ^ ((lane >> 3) & 3)) * 8);
  const int swr = ((fq ^ ((fr >> 1) & 3)) * 8);
  const int srow = lane >> 2;

  const int e0 = route_e[b * TOPK + 0];
  const int e1 = route_e[b * TOPK + 1];
  const int e2 = route_e[b * TOPK + 2];
  const bf16* A0 = hbuf + ((size_t)(b * TOPK + 0) * SR + m0) * D_FF;
  const bf16* A1 = hbuf + ((size_t)(b * TOPK + 1) * SR + m0) * D_FF;
  const bf16* A2 = hbuf + ((size_t)(b * TOPK + 2) * SR + m0) * D_FF;
  const bf16* B0 = WbT + ((size_t)e0 * D_MODEL + n0) * D_FF;
  const bf16* B1 = WbT + ((size_t)e1 * D_MODEL + n0) * D_FF;
  const bf16* B2 = WbT + ((size_t)e2 * D_MODEL + n0) * D_FF;

  f32x4 acc[8][4] = {};
  bf16x8 bfr[4];

  // prologue: tile 0 = rank 0, kt 0
  STAGE1(A0, D_FF, 0,  &As[0]);
  STAGE1(B0, D_FF, 0,  &Bs[0]);
  STAGE1(A0, D_FF, 32, &As[8192]);
  STAGE1(B0, D_FF, 32, &Bs[8192]);

  const int NT = TOPK * (D_FF / 64);  // 192, rank-major
  for (int t = 0; t < NT; ++t) {
    const int buf = t & 1, nbuf = buf ^ 1;
    const int gn = (t + 1 < NT) ? t + 1 : NT - 1;
    const int rn = gn >> 6;
    const int cb = (gn & 63) * 64;
    const bf16* Agn = rn == 0 ? A0 : (rn == 1 ? A1 : A2);
    const bf16* Bgn = rn == 0 ? B0 : (rn == 1 ? B1 : B2);
    STAGE1(Agn, D_FF, cb,      &As[(nbuf * 2 + 0) * 8192]);  SYNC6(); LOADB(0); MFMA16(0, 0);
    STAGE1(Bgn, D_FF, cb,      &Bs[(nbuf * 2 + 0) * 8192]);  SYNC6();           MFMA16(0, 1);
    STAGE1(Agn, D_FF, cb + 32, &As[(nbuf * 2 + 1) * 8192]);  SYNC6(); LOADB(1); MFMA16(1, 0);
    STAGE1(Bgn, D_FF, cb + 32, &Bs[(nbuf * 2 + 1) * 8192]);  SYNC6();           MFMA16(1, 1);
  }

  // epilogue: residual add, f32 out
  const size_t ob = ((size_t)b * SEQ + (size_t)(s_base + m0 + wm * 128)) * D_MODEL + n0 + wn * 64;
#pragma unroll
  for (int MI = 0; MI < 8; ++MI)
#pragma unroll
    for (int ni = 0; ni < 4; ++ni)
#pragma unroll
      for (int j = 0; j < 4; ++j) {
        size_t idx = ob + (size_t)(MI * 16 + fq * 4 + j) * D_MODEL + ni * 16 + fr;
        out[idx] = x[idx] + acc[MI][ni][j];
      }
}

// ---------------- sentinel ----------------

__global__ void fail_kernel(float* out, float v) {
  if (threadIdx.x < 64) out[threadIdx.x] = v;
}

// ---------------- host ----------------

extern "C" void kernel_launch(void* const* d_in, const int* in_sizes, int n_in,
                              void* d_out, int out_size, void* d_ws, size_t ws_size,
                              hipStream_t stream) {
  const float* x  = (const float*)d_in[0];
  const float* W1 = (const float*)d_in[1];
  const float* b1 = (const float*)d_in[2];
  const float* W2 = (const float*)d_in[3];
  const float* b2 = (const float*)d_in[4];
  const float* Wa = (const float*)d_in[5];
  const float* Wb = (const float*)d_in[6];
  float* out = (float*)d_out;

  char* ws = (char*)d_ws;
  size_t off = 0;
  auto walloc = [&](size_t bytes) -> void* {
    void* p = ws + off;
    off += (bytes + 255) & ~(size_t)255;
    return p;
  };

  float* partial = (float*)walloc((size_t)8 * BATCH * D_MODEL * 4);
  float* pooled  = (float*)walloc((size_t)BATCH * D_MODEL * 4);
  int*   route_e = (int*)walloc(NPAIR * 4);
  float* route_w = (float*)walloc(NPAIR * 4);
  bf16*  xb      = (bf16*)walloc((size_t)BATCH * SEQ * D_MODEL * 2);
  bf16*  WaT     = (bf16*)walloc((size_t)N_ZONES * D_MODEL * D_FF * 2);
  bf16*  WbT     = (bf16*)walloc((size_t)N_ZONES * D_MODEL * D_FF * 2);
  size_t fixed = off;

  int SR = 0;
  const int cands[3] = {1024, 512, 256};  // prefer 1024: gemm2 grid = 256 blocks = full GPU
  for (int ci = 0; ci < 3; ++ci) {
    size_t need = fixed + (size_t)NPAIR * cands[ci] * D_FF * 2 + 1024;
    if (need <= ws_size) { SR = cands[ci]; break; }
  }
  if (SR == 0) {
    fail_kernel<<<1, 64, 0, stream>>>(out, 1.0e6f + (float)(ws_size >> 20));
    return;
  }
  bf16* hbuf = (bf16*)walloc((size_t)NPAIR * SR * D_FF * 2);

  pool_partial_kernel<<<dim3(8, BATCH), 256, 0, stream>>>(x, partial);
  pool_final_kernel<<<BATCH, 256, 0, stream>>>(partial, pooled);
  router_kernel<<<BATCH, RH, 0, stream>>>(pooled, W1, b1, W2, b2, route_e, route_w);

  convert_x_kernel<<<(BATCH * SEQ * D_MODEL) / (256 * 8), 256, 0, stream>>>(x, xb);
  transpose_kernel<<<dim3(D_FF / 64, D_MODEL / 64, N_ZONES), 256, 0, stream>>>(Wa, WaT, D_MODEL, D_FF);
  transpose_kernel<<<dim3(D_MODEL / 64, D_FF / 64, N_ZONES), 256, 0, stream>>>(Wb, WbT, D_FF, D_MODEL);

  const int NS = SEQ / SR;
  for (int sl = 0; sl < NS; ++sl) {
    gemm1_kernel<<<dim3(D_FF / 256, SR / 256, NPAIR), 512, 0, stream>>>(
        xb, WaT, route_e, route_w, hbuf, sl * SR, SR);
    gemm2_kernel<<<dim3(D_MODEL / 256, SR / 256, BATCH), 512, 0, stream>>>(
        hbuf, WbT, route_e, x, out, sl * SR, SR);
  }
}

// Round 5
// 2608.735 us; speedup vs baseline: 1.3120x; 1.0911x over previous
//
#include <hip/hip_runtime.h>
#include <hip/hip_bf16.h>
#include <stdint.h>

#define D_MODEL 1024
#define D_FF    4096
#define N_ZONES 8
#define TOPK    3
#define RH      256
#define BATCH   16
#define SEQ     2048
#define NPAIR   (BATCH * TOPK)

typedef __bf16 bf16;
typedef __bf16 bf16x8 __attribute__((ext_vector_type(8)));
typedef float  f32x4  __attribute__((ext_vector_type(4)));

// ---------------- helpers ----------------

__device__ __forceinline__ void gload16(const void* g, void* l) {
  __builtin_amdgcn_global_load_lds((const __attribute__((address_space(1))) void*)g,
                                   (__attribute__((address_space(3))) void*)l,
                                   16, 0, 0);
}

__device__ __forceinline__ float gelu_tanh(float x) {
  float inner = 0.7978845608028654f * (x + 0.044715f * x * x * x);
  float t = __expf(2.0f * inner);
  float th = 1.0f - 2.0f / (t + 1.0f);
  return 0.5f * x * (1.0f + th);
}

// bijective XCD swizzle: consecutive remapped ids stay on one XCD (grid%8==0 for all our grids)
__device__ __forceinline__ void xcd_remap(int& bx, int& by, int& bz) {
  int lin = blockIdx.x + gridDim.x * (blockIdx.y + gridDim.y * blockIdx.z);
  int nwg = gridDim.x * gridDim.y * gridDim.z;
  int ns  = (lin & 7) * (nwg >> 3) + (lin >> 3);
  bx = ns % gridDim.x; int rest = ns / gridDim.x;
  by = rest % gridDim.y; bz = rest / gridDim.y;
}

// ---------------- pooling ----------------

__global__ void pool_partial_kernel(const float* __restrict__ x, float* __restrict__ partial) {
  int sc = blockIdx.x;
  int b  = blockIdx.y;
  int tid = threadIdx.x;
  const float* xp = x + ((size_t)b * SEQ + (size_t)sc * 256) * D_MODEL;
  for (int i = 0; i < D_MODEL / 256; ++i) {
    int d = tid + i * 256;
    float s = 0.f;
    for (int ss = 0; ss < 256; ++ss) s += xp[(size_t)ss * D_MODEL + d];
    partial[((size_t)sc * BATCH + b) * D_MODEL + d] = s;
  }
}

__global__ void pool_final_kernel(const float* __restrict__ partial, float* __restrict__ pooled) {
  int b = blockIdx.x;
  int tid = threadIdx.x;
  for (int i = 0; i < D_MODEL / 256; ++i) {
    int d = tid + i * 256;
    float s = 0.f;
    for (int sc = 0; sc < 8; ++sc) s += partial[((size_t)sc * BATCH + b) * D_MODEL + d];
    pooled[b * D_MODEL + d] = s * (1.0f / SEQ);
  }
}

// ---------------- router ----------------

__global__ void router_kernel(const float* __restrict__ pooled,
                              const float* __restrict__ W1, const float* __restrict__ b1,
                              const float* __restrict__ W2, const float* __restrict__ b2,
                              int* __restrict__ route_e, float* __restrict__ route_w) {
  __shared__ float pld[D_MODEL];
  __shared__ float hls[RH];
  __shared__ float lg[N_ZONES];
  const int b = blockIdx.x;
  const int j = threadIdx.x;

  for (int i = 0; i < D_MODEL / RH; ++i) pld[j + i * RH] = pooled[b * D_MODEL + j + i * RH];
  __syncthreads();

  float acc = b1[j];
#pragma unroll 8
  for (int k = 0; k < D_MODEL; ++k) acc += pld[k] * W1[k * RH + j];
  hls[j] = tanhf(acc);
  __syncthreads();

  if (j < N_ZONES) {
    float s = b2[j];
    for (int t = 0; t < RH; ++t) s += hls[t] * W2[t * N_ZONES + j];
    lg[j] = s;
  }
  __syncthreads();

  if (j == 0) {
    float m = lg[0];
    for (int e = 1; e < N_ZONES; ++e) m = fmaxf(m, lg[e]);
    float p[N_ZONES]; float sum = 0.f;
    for (int e = 0; e < N_ZONES; ++e) { p[e] = expf(lg[e] - m); sum += p[e]; }
    int used[N_ZONES] = {0};
    int idx[TOPK]; float tv[TOPK]; float tsum = 0.f;
    for (int r = 0; r < TOPK; ++r) {
      int best = 0; float bv = -1.f;
      for (int e = 0; e < N_ZONES; ++e)
        if (!used[e] && p[e] > bv) { bv = p[e]; best = e; }
      used[best] = 1; idx[r] = best; tv[r] = bv / sum; tsum += bv / sum;
    }
    for (int r = 0; r < TOPK; ++r) {
      route_e[b * TOPK + r] = idx[r];
      route_w[b * TOPK + r] = tv[r] / tsum;
    }
  }
}

// ---------------- conversions ----------------

__global__ void convert_x_kernel(const float* __restrict__ x, bf16* __restrict__ xb) {
  size_t i = ((size_t)blockIdx.x * blockDim.x + threadIdx.x) * 8;
  const float4* p = (const float4*)(x + i);
  float4 v0 = p[0], v1 = p[1];
  bf16x8 o;
  o[0] = (bf16)v0.x; o[1] = (bf16)v0.y; o[2] = (bf16)v0.z; o[3] = (bf16)v0.w;
  o[4] = (bf16)v1.x; o[5] = (bf16)v1.y; o[6] = (bf16)v1.z; o[7] = (bf16)v1.w;
  *(bf16x8*)(xb + i) = o;
}

__global__ void transpose_kernel(const float* __restrict__ src, bf16* __restrict__ dst, int R, int C) {
  __shared__ float tile[64][65];
  int e = blockIdx.z;
  const float* s = src + (size_t)e * R * C;
  bf16* d = dst + (size_t)e * R * C;
  int r0 = blockIdx.y * 64, c0 = blockIdx.x * 64;
  int tc = threadIdx.x & 63, tr4 = threadIdx.x >> 6;
  for (int i = 0; i < 16; ++i) {
    int r = i * 4 + tr4;
    tile[r][tc] = s[(size_t)(r0 + r) * C + (c0 + tc)];
  }
  __syncthreads();
  for (int i = 0; i < 16; ++i) {
    int cc = i * 4 + tr4;
    d[(size_t)(c0 + cc) * R + (r0 + tc)] = (bf16)tile[tc][cc];
  }
}

// ---------------- 128x256 ring-3 pipelined GEMM core ----------------
// Tile BM=128 (rows), BN=256 (cols), BK=64 (2 k-halves of 32). 8 waves (2m x 4n),
// per-wave 64x64, acc 4x4 f32x4. LDS ring of 3 K-tiles:
//   As[3][2][128*32] = 48KB, Bs[3][2][256*32] = 96KB -> 144KB total.
// Phase (one kh): vmcnt(6); s_barrier; ds_read NEXT phase frags (8 b128);
//   stage tile t+2 half (3 gload_lds); lgkmcnt(8); 16 MFMA on current frags.
// vmcnt(6): at each phase's vmcnt, 3 stage-ops (9 loads) may be outstanding;
// retiring to 6 completes exactly the half-tile the post-barrier reads need.
// Ring-3 => stage writes slot (t+2)%3 never alias read slot t%3, 1 barrier/phase.

#define PSTAGE(slot_, kh_, SA_, SB_, sld_, scol_)                              \
  { const bf16* _sa = (SA_) + (size_t)(w * 16 + srow) * (sld_) + (scol_) + swz; \
    gload16(_sa, &As[((slot_) * 2 + (kh_)) * 4096] + w * 512);                  \
    const bf16* _sb = (SB_) + (size_t)(w * 16 + srow) * (sld_) + (scol_) + swz; \
    gload16(_sb, &Bs[((slot_) * 2 + (kh_)) * 8192] + w * 512);                  \
    gload16(_sb + (size_t)128 * (sld_), &Bs[((slot_) * 2 + (kh_)) * 8192] + 4096 + w * 512); }

#define DSRD(AF_, BF_, slot_, kh_)                                             \
  { const bf16* Ah = &As[((slot_) * 2 + (kh_)) * 4096] + (size_t)(wm * 64 + fr) * 32 + swr; \
    const bf16* Bh = &Bs[((slot_) * 2 + (kh_)) * 8192] + (size_t)(wn * 64 + fr) * 32 + swr; \
    _Pragma("unroll")                                                          \
    for (int i = 0; i < 4; ++i) {                                              \
      AF_[i] = *(const bf16x8*)(Ah + i * 512);                                 \
      BF_[i] = *(const bf16x8*)(Bh + i * 512);                                 \
    } }

#define PHASE(curA, curB, nxtA, nxtB, rslot_, rkh_, sslot_, skh_, SA_, SB_, sld_, scb_) \
  { asm volatile("s_waitcnt vmcnt(6)" ::: "memory");                           \
    __builtin_amdgcn_s_barrier();                                              \
    __builtin_amdgcn_sched_barrier(0);                                         \
    DSRD(nxtA, nxtB, rslot_, rkh_);                                            \
    PSTAGE(sslot_, skh_, SA_, SB_, sld_, (scb_) + (skh_) * 32);                \
    asm volatile("s_waitcnt lgkmcnt(8)" ::: "memory");                         \
    __builtin_amdgcn_sched_barrier(0);                                         \
    __builtin_amdgcn_s_setprio(1);                                             \
    _Pragma("unroll")                                                          \
    for (int mi = 0; mi < 4; ++mi)                                             \
      _Pragma("unroll")                                                        \
      for (int ni = 0; ni < 4; ++ni)                                           \
        acc[mi][ni] = __builtin_amdgcn_mfma_f32_16x16x32_bf16(curA[mi], curB[ni], acc[mi][ni], 0, 0, 0); \
    __builtin_amdgcn_s_setprio(0); }

#define GEMM_DECLS                                                             \
  const int tid = threadIdx.x;                                                 \
  const int lane = tid & 63;                                                   \
  const int w = tid >> 6;                                                      \
  const int wm = w >> 2, wn = w & 3;                                           \
  const int fr = lane & 15, fq = lane >> 4;                                    \
  const int swz = (((lane & 3) ^ ((lane >> 3) & 3)) * 8);                      \
  const int swr = ((fq ^ ((fr >> 1) & 3)) * 8);                                \
  const int srow = lane >> 2;                                                  \
  f32x4 acc[4][4] = {};                                                        \
  bf16x8 afA[4], bfA[4], afB[4], bfB[4];

// GEMM1: h = gelu(xb @ Wa[e]) * w_r ; A=[SR,1024] rm, B^T=[4096,1024] rm
__launch_bounds__(512, 2)
__global__ void gemm1_kernel(const bf16* __restrict__ xb, const bf16* __restrict__ WaT,
                             const int* __restrict__ route_e, const float* __restrict__ route_w,
                             bf16* __restrict__ hbuf, int s_base, int SR) {
  __shared__ bf16 As[3 * 2 * 4096];
  __shared__ bf16 Bs[3 * 2 * 8192];
  int bx, by, bz;
  xcd_remap(bx, by, bz);
  const int pair = bz;
  const int b = pair / TOPK;
  const int e = route_e[pair];
  const float wr = route_w[pair];
  const int m0 = by * 128;
  const int n0 = bx * 256;
  GEMM_DECLS

  const bf16* Ag = xb  + ((size_t)b * SEQ + (size_t)(s_base + m0)) * D_MODEL;
  const bf16* Bg = WaT + ((size_t)e * D_FF + n0) * D_MODEL;

  // prologue: tiles 0,1 -> slots 0,1 (12 loads); then pre-read phase(0,0) frags
  PSTAGE(0, 0, Ag, Bg, D_MODEL, 0);
  PSTAGE(0, 1, Ag, Bg, D_MODEL, 32);
  PSTAGE(1, 0, Ag, Bg, D_MODEL, 64);
  PSTAGE(1, 1, Ag, Bg, D_MODEL, 96);
  asm volatile("s_waitcnt vmcnt(9)" ::: "memory");
  __builtin_amdgcn_s_barrier();
  __builtin_amdgcn_sched_barrier(0);
  DSRD(afA, bfA, 0, 0);

  const int NT = D_MODEL / 64;  // 16
  int sl = 0;
  for (int t = 0; t < NT; ++t) {
    int sp = sl + 2; if (sp >= 3) sp -= 3;
    int sln = sl + 1; if (sln >= 3) sln -= 3;
    const int tn = (t + 2 < NT) ? t + 2 : NT - 1;   // clamped tail keeps window uniform
    const int cb = tn * 64;
    PHASE(afA, bfA, afB, bfB, sl, 1, sp, 0, Ag, Bg, D_MODEL, cb);   // MFMA kh0, read kh1
    PHASE(afB, bfB, afA, bfA, sln, 0, sp, 1, Ag, Bg, D_MODEL, cb);  // MFMA kh1, read next kh0
    sl = sln;
  }

  // epilogue: gelu * wr, bf16 store
  bf16* hout = hbuf + ((size_t)pair * SR + m0 + wm * 64) * D_FF + n0 + wn * 64;
#pragma unroll
  for (int mi = 0; mi < 4; ++mi)
#pragma unroll
    for (int ni = 0; ni < 4; ++ni)
#pragma unroll
      for (int j = 0; j < 4; ++j) {
        float v = acc[mi][ni][j];
        hout[(size_t)(mi * 16 + fq * 4 + j) * D_FF + ni * 16 + fr] = (bf16)(gelu_tanh(v) * wr);
      }
}

// GEMM2: out = x + sum_r h[b,r] @ Wb[e_r]
__launch_bounds__(512, 2)
__global__ void gemm2_kernel(const bf16* __restrict__ hbuf, const bf16* __restrict__ WbT,
                             const int* __restrict__ route_e,
                             const float* __restrict__ x, float* __restrict__ out,
                             int s_base, int SR) {
  __shared__ bf16 As[3 * 2 * 4096];
  __shared__ bf16 Bs[3 * 2 * 8192];
  int bx, by, bz;
  xcd_remap(bx, by, bz);
  const int b = bz;
  const int m0 = by * 128;
  const int n0 = bx * 256;
  GEMM_DECLS

  const int e0 = route_e[b * TOPK + 0];
  const int e1 = route_e[b * TOPK + 1];
  const int e2 = route_e[b * TOPK + 2];
  const bf16* A0 = hbuf + ((size_t)(b * TOPK + 0) * SR + m0) * D_FF;
  const bf16* A1 = hbuf + ((size_t)(b * TOPK + 1) * SR + m0) * D_FF;
  const bf16* A2 = hbuf + ((size_t)(b * TOPK + 2) * SR + m0) * D_FF;
  const bf16* B0 = WbT + ((size_t)e0 * D_MODEL + n0) * D_FF;
  const bf16* B1 = WbT + ((size_t)e1 * D_MODEL + n0) * D_FF;
  const bf16* B2 = WbT + ((size_t)e2 * D_MODEL + n0) * D_FF;

  // prologue: K-tiles 0,1 (rank 0) -> slots 0,1
  PSTAGE(0, 0, A0, B0, D_FF, 0);
  PSTAGE(0, 1, A0, B0, D_FF, 32);
  PSTAGE(1, 0, A0, B0, D_FF, 64);
  PSTAGE(1, 1, A0, B0, D_FF, 96);
  asm volatile("s_waitcnt vmcnt(9)" ::: "memory");
  __builtin_amdgcn_s_barrier();
  __builtin_amdgcn_sched_barrier(0);
  DSRD(afA, bfA, 0, 0);

  const int NT = TOPK * (D_FF / 64);  // 192, rank-major
  int sl = 0;
  for (int t = 0; t < NT; ++t) {
    int sp = sl + 2; if (sp >= 3) sp -= 3;
    int sln = sl + 1; if (sln >= 3) sln -= 3;
    const int tn = (t + 2 < NT) ? t + 2 : NT - 1;
    const int rn = tn >> 6;
    const bf16* SA = rn == 0 ? A0 : (rn == 1 ? A1 : A2);
    const bf16* SB = rn == 0 ? B0 : (rn == 1 ? B1 : B2);
    const int cb = (tn & 63) * 64;
    PHASE(afA, bfA, afB, bfB, sl, 1, sp, 0, SA, SB, D_FF, cb);
    PHASE(afB, bfB, afA, bfA, sln, 0, sp, 1, SA, SB, D_FF, cb);
    sl = sln;
  }

  // epilogue: residual add, f32 out
  const size_t ob = ((size_t)b * SEQ + (size_t)(s_base + m0 + wm * 64)) * D_MODEL + n0 + wn * 64;
#pragma unroll
  for (int mi = 0; mi < 4; ++mi)
#pragma unroll
    for (int ni = 0; ni < 4; ++ni)
#pragma unroll
      for (int j = 0; j < 4; ++j) {
        size_t idx = ob + (size_t)(mi * 16 + fq * 4 + j) * D_MODEL + ni * 16 + fr;
        out[idx] = x[idx] + acc[mi][ni][j];
      }
}

// ---------------- sentinel ----------------

__global__ void fail_kernel(float* out, float v) {
  if (threadIdx.x < 64) out[threadIdx.x] = v;
}

// ---------------- host ----------------

extern "C" void kernel_launch(void* const* d_in, const int* in_sizes, int n_in,
                              void* d_out, int out_size, void* d_ws, size_t ws_size,
                              hipStream_t stream) {
  const float* x  = (const float*)d_in[0];
  const float* W1 = (const float*)d_in[1];
  const float* b1 = (const float*)d_in[2];
  const float* W2 = (const float*)d_in[3];
  const float* b2 = (const float*)d_in[4];
  const float* Wa = (const float*)d_in[5];
  const float* Wb = (const float*)d_in[6];
  float* out = (float*)d_out;

  char* ws = (char*)d_ws;
  size_t off = 0;
  auto walloc = [&](size_t bytes) -> void* {
    void* p = ws + off;
    off += (bytes + 255) & ~(size_t)255;
    return p;
  };

  float* partial = (float*)walloc((size_t)8 * BATCH * D_MODEL * 4);
  float* pooled  = (float*)walloc((size_t)BATCH * D_MODEL * 4);
  int*   route_e = (int*)walloc(NPAIR * 4);
  float* route_w = (float*)walloc(NPAIR * 4);
  bf16*  xb      = (bf16*)walloc((size_t)BATCH * SEQ * D_MODEL * 2);
  bf16*  WaT     = (bf16*)walloc((size_t)N_ZONES * D_MODEL * D_FF * 2);
  bf16*  WbT     = (bf16*)walloc((size_t)N_ZONES * D_MODEL * D_FF * 2);
  size_t fixed = off;

  int SR = 0;
  const int cands[2] = {512, 256};   // SR=512: ws total ~403MB; gemm2 grid 4x4x16 = full GPU
  for (int ci = 0; ci < 2; ++ci) {
    size_t need = fixed + (size_t)NPAIR * cands[ci] * D_FF * 2 + 1024;
    if (need <= ws_size) { SR = cands[ci]; break; }
  }
  if (SR == 0) {
    fail_kernel<<<1, 64, 0, stream>>>(out, 1.0e6f + (float)(ws_size >> 20));
    return;
  }
  bf16* hbuf = (bf16*)walloc((size_t)NPAIR * SR * D_FF * 2);

  pool_partial_kernel<<<dim3(8, BATCH), 256, 0, stream>>>(x, partial);
  pool_final_kernel<<<BATCH, 256, 0, stream>>>(partial, pooled);
  router_kernel<<<BATCH, RH, 0, stream>>>(pooled, W1, b1, W2, b2, route_e, route_w);

  convert_x_kernel<<<(BATCH * SEQ * D_MODEL) / (256 * 8), 256, 0, stream>>>(x, xb);
  transpose_kernel<<<dim3(D_FF / 64, D_MODEL / 64, N_ZONES), 256, 0, stream>>>(Wa, WaT, D_MODEL, D_FF);
  transpose_kernel<<<dim3(D_MODEL / 64, D_FF / 64, N_ZONES), 256, 0, stream>>>(Wb, WbT, D_FF, D_MODEL);

  const int NS = SEQ / SR;
  for (int sl = 0; sl < NS; ++sl) {
    gemm1_kernel<<<dim3(D_FF / 256, SR / 128, NPAIR), 512, 0, stream>>>(
        xb, WaT, route_e, route_w, hbuf, sl * SR, SR);
    gemm2_kernel<<<dim3(D_MODEL / 256, SR / 128, BATCH), 512, 0, stream>>>(
        hbuf, WbT, route_e, x, out, sl * SR, SR);
  }
}

// Round 6
// 2368.901 us; speedup vs baseline: 1.4449x; 1.1012x over previous
//
#include <hip/hip_runtime.h>
#include <hip/hip_bf16.h>
#include <stdint.h>

#define D_MODEL 1024
#define D_FF    4096
#define N_ZONES 8
#define TOPK    3
#define RH      256
#define BATCH   16
#define SEQ     2048
#define NPAIR   (BATCH * TOPK)

typedef __bf16 bf16;
typedef __bf16 bf16x8 __attribute__((ext_vector_type(8)));
typedef float  f32x4  __attribute__((ext_vector_type(4)));

// ---------------- helpers ----------------

__device__ __forceinline__ void gload16(const void* g, void* l) {
  __builtin_amdgcn_global_load_lds((const __attribute__((address_space(1))) void*)g,
                                   (__attribute__((address_space(3))) void*)l,
                                   16, 0, 0);
}

__device__ __forceinline__ float gelu_tanh(float x) {
  float inner = 0.7978845608028654f * (x + 0.044715f * x * x * x);
  float t = __expf(2.0f * inner);
  float th = 1.0f - 2.0f / (t + 1.0f);
  return 0.5f * x * (1.0f + th);
}

// bijective XCD swizzle: each XCD gets a contiguous chunk of remapped ids (grid%8==0)
__device__ __forceinline__ void xcd_remap(int& bx, int& by, int& bz) {
  int lin = blockIdx.x + gridDim.x * (blockIdx.y + gridDim.y * blockIdx.z);
  int nwg = gridDim.x * gridDim.y * gridDim.z;
  int ns  = (lin & 7) * (nwg >> 3) + (lin >> 3);
  bx = ns % gridDim.x; int rest = ns / gridDim.x;
  by = rest % gridDim.y; bz = rest / gridDim.y;
}

// ---------------- pooling ----------------

__global__ void pool_partial_kernel(const float* __restrict__ x, float* __restrict__ partial) {
  int sc = blockIdx.x;
  int b  = blockIdx.y;
  int tid = threadIdx.x;
  const float* xp = x + ((size_t)b * SEQ + (size_t)sc * 256) * D_MODEL;
  for (int i = 0; i < D_MODEL / 256; ++i) {
    int d = tid + i * 256;
    float s = 0.f;
    for (int ss = 0; ss < 256; ++ss) s += xp[(size_t)ss * D_MODEL + d];
    partial[((size_t)sc * BATCH + b) * D_MODEL + d] = s;
  }
}

__global__ void pool_final_kernel(const float* __restrict__ partial, float* __restrict__ pooled) {
  int b = blockIdx.x;
  int tid = threadIdx.x;
  for (int i = 0; i < D_MODEL / 256; ++i) {
    int d = tid + i * 256;
    float s = 0.f;
    for (int sc = 0; sc < 8; ++sc) s += partial[((size_t)sc * BATCH + b) * D_MODEL + d];
    pooled[b * D_MODEL + d] = s * (1.0f / SEQ);
  }
}

// ---------------- router ----------------

__global__ void router_kernel(const float* __restrict__ pooled,
                              const float* __restrict__ W1, const float* __restrict__ b1,
                              const float* __restrict__ W2, const float* __restrict__ b2,
                              int* __restrict__ route_e, float* __restrict__ route_w) {
  __shared__ float pld[D_MODEL];
  __shared__ float hls[RH];
  __shared__ float lg[N_ZONES];
  const int b = blockIdx.x;
  const int j = threadIdx.x;

  for (int i = 0; i < D_MODEL / RH; ++i) pld[j + i * RH] = pooled[b * D_MODEL + j + i * RH];
  __syncthreads();

  float acc = b1[j];
#pragma unroll 8
  for (int k = 0; k < D_MODEL; ++k) acc += pld[k] * W1[k * RH + j];
  hls[j] = tanhf(acc);
  __syncthreads();

  if (j < N_ZONES) {
    float s = b2[j];
    for (int t = 0; t < RH; ++t) s += hls[t] * W2[t * N_ZONES + j];
    lg[j] = s;
  }
  __syncthreads();

  if (j == 0) {
    float m = lg[0];
    for (int e = 1; e < N_ZONES; ++e) m = fmaxf(m, lg[e]);
    float p[N_ZONES]; float sum = 0.f;
    for (int e = 0; e < N_ZONES; ++e) { p[e] = expf(lg[e] - m); sum += p[e]; }
    int used[N_ZONES] = {0};
    int idx[TOPK]; float tv[TOPK]; float tsum = 0.f;
    for (int r = 0; r < TOPK; ++r) {
      int best = 0; float bv = -1.f;
      for (int e = 0; e < N_ZONES; ++e)
        if (!used[e] && p[e] > bv) { bv = p[e]; best = e; }
      used[best] = 1; idx[r] = best; tv[r] = bv / sum; tsum += bv / sum;
    }
    for (int r = 0; r < TOPK; ++r) {
      route_e[b * TOPK + r] = idx[r];
      route_w[b * TOPK + r] = tv[r] / tsum;
    }
  }
}

// stable counting-sort of the 48 pairs by expert id -> perm (gemm1 XCD locality)
__global__ void sort_pairs_kernel(const int* __restrict__ route_e, int* __restrict__ perm) {
  if (threadIdx.x == 0 && blockIdx.x == 0) {
    int p = 0;
    for (int e = 0; e < N_ZONES; ++e)
      for (int i = 0; i < NPAIR; ++i)
        if (route_e[i] == e) perm[p++] = i;
  }
}

// ---------------- conversions ----------------

__global__ void convert_x_kernel(const float* __restrict__ x, bf16* __restrict__ xb) {
  size_t i = ((size_t)blockIdx.x * blockDim.x + threadIdx.x) * 8;
  const float4* p = (const float4*)(x + i);
  float4 v0 = p[0], v1 = p[1];
  bf16x8 o;
  o[0] = (bf16)v0.x; o[1] = (bf16)v0.y; o[2] = (bf16)v0.z; o[3] = (bf16)v0.w;
  o[4] = (bf16)v1.x; o[5] = (bf16)v1.y; o[6] = (bf16)v1.z; o[7] = (bf16)v1.w;
  *(bf16x8*)(xb + i) = o;
}

__global__ void transpose_kernel(const float* __restrict__ src, bf16* __restrict__ dst, int R, int C) {
  __shared__ float tile[64][65];
  int e = blockIdx.z;
  const float* s = src + (size_t)e * R * C;
  bf16* d = dst + (size_t)e * R * C;
  int r0 = blockIdx.y * 64, c0 = blockIdx.x * 64;
  int tc = threadIdx.x & 63, tr4 = threadIdx.x >> 6;
  for (int i = 0; i < 16; ++i) {
    int r = i * 4 + tr4;
    tile[r][tc] = s[(size_t)(r0 + r) * C + (c0 + tc)];
  }
  __syncthreads();
  for (int i = 0; i < 16; ++i) {
    int cc = i * 4 + tr4;
    d[(size_t)(c0 + cc) * R + (r0 + tc)] = (bf16)tile[tc][cc];
  }
}

// =====================================================================
// GEMM1: 256x256 fat-phase ring-2.
// LDS per operand: [2 buf][2 kstep][256 rows][32 k] bf16 (16KB each) = 64KB; A+B = 128KB.
// 8 waves (2m x 4n), wave tile 128x64, acc[8][4] f32x4.
// Phase = one (tile, kstep): vmcnt(4); barrier; 12x ds_read_b128 (this phase's frags,
// staged 2 phases ago); stage next tile's matching kstep (4 gloads); lgkmcnt(0); 32 MFMA.
// vmcnt(4): 8 outstanding at wait point; retiring to 4 completes exactly the 2-phases-ago
// half while the previous phase's 4 stay in flight (counted, never 0 in loop).
// Swizzle pair (proven conflict-0 in r5): source col ^= ((lane&3)^((srow>>1)&3))*8,
// read col ^= (fq^((fr>>1)&3))*8 -> 2-way (free) bank aliasing.
// =====================================================================

#define G1_PSTAGE4(buf_, ks_, kcb_)                                            \
  { const bf16* _sa = Ag + (size_t)(w * 16 + srow) * D_MODEL + (kcb_) + swz;   \
    bf16* _la = &As[((buf_) * 2 + (ks_)) * 8192] + w * 512;                    \
    gload16(_sa, _la);                                                         \
    gload16(_sa + (size_t)128 * D_MODEL, _la + 4096);                          \
    const bf16* _sb = Bg + (size_t)(w * 16 + srow) * D_MODEL + (kcb_) + swz;   \
    bf16* _lb = &Bs[((buf_) * 2 + (ks_)) * 8192] + w * 512;                    \
    gload16(_sb, _lb);                                                         \
    gload16(_sb + (size_t)128 * D_MODEL, _lb + 4096); }

#define G1_DSRD12(buf_, ks_)                                                   \
  { const bf16* Ah = &As[((buf_) * 2 + (ks_)) * 8192] + (size_t)(wm * 128 + fr) * 32 + swr; \
    _Pragma("unroll")                                                          \
    for (int i = 0; i < 8; ++i) fA[i] = *(const bf16x8*)(Ah + i * 512);        \
    const bf16* Bh = &Bs[((buf_) * 2 + (ks_)) * 8192] + (size_t)(wn * 64 + fr) * 32 + swr; \
    _Pragma("unroll")                                                          \
    for (int i = 0; i < 4; ++i) fB[i] = *(const bf16x8*)(Bh + i * 512); }

#define G1_FPHASE(rbuf_, rks_, sbuf_, sks_, kcb_)                              \
  { asm volatile("s_waitcnt vmcnt(4)" ::: "memory");                           \
    __builtin_amdgcn_s_barrier();                                              \
    __builtin_amdgcn_sched_barrier(0);                                         \
    G1_DSRD12(rbuf_, rks_);                                                    \
    G1_PSTAGE4(sbuf_, sks_, kcb_);                                             \
    asm volatile("s_waitcnt lgkmcnt(0)" ::: "memory");                         \
    __builtin_amdgcn_sched_barrier(0);                                         \
    __builtin_amdgcn_s_setprio(1);                                             \
    _Pragma("unroll")                                                          \
    for (int mi = 0; mi < 8; ++mi)                                             \
      _Pragma("unroll")                                                        \
      for (int ni = 0; ni < 4; ++ni)                                           \
        acc[mi][ni] = __builtin_amdgcn_mfma_f32_16x16x32_bf16(fA[mi], fB[ni], acc[mi][ni], 0, 0, 0); \
    __builtin_amdgcn_s_setprio(0); }

__launch_bounds__(512, 2)
__global__ void gemm1_kernel(const bf16* __restrict__ xb, const bf16* __restrict__ WaT,
                             const int* __restrict__ route_e, const float* __restrict__ route_w,
                             const int* __restrict__ perm,
                             bf16* __restrict__ hbuf, int s_base, int SR) {
  __shared__ bf16 As[2 * 2 * 8192];
  __shared__ bf16 Bs[2 * 2 * 8192];
  int bx, by, bz;
  xcd_remap(bx, by, bz);
  const int pair = perm[bz];          // expert-sorted: XCD chunk shares WaT panels
  const int b = pair / TOPK;
  const int e = route_e[pair];
  const float wr = route_w[pair];
  const int m0 = by * 256;
  const int n0 = bx * 256;
  const int tid = threadIdx.x;
  const int lane = tid & 63;
  const int w = tid >> 6;
  const int wm = w >> 2, wn = w & 3;
  const int fr = lane & 15, fq = lane >> 4;
  const int swz = (((lane & 3) ^ ((lane >> 3) & 3)) * 8);
  const int swr = ((fq ^ ((fr >> 1) & 3)) * 8);
  const int srow = lane >> 2;

  const bf16* Ag = xb  + ((size_t)b * SEQ + (size_t)(s_base + m0)) * D_MODEL;
  const bf16* Bg = WaT + ((size_t)e * D_FF + n0) * D_MODEL;

  f32x4 acc[8][4] = {};
  bf16x8 fA[8], fB[4];

  // prologue: tile 0, both k-steps -> buf 0 (8 loads outstanding)
  G1_PSTAGE4(0, 0, 0);
  G1_PSTAGE4(0, 1, 32);

  const int NT = D_MODEL / 64;  // 16
  int buf = 0;
  for (int t = 0; t < NT; ++t) {
    const int tn = (t + 1 < NT) ? t + 1 : NT - 1;   // clamped dummy tail keeps window uniform
    const int cb = tn * 64;
    G1_FPHASE(buf, 0, buf ^ 1, 0, cb);
    G1_FPHASE(buf, 1, buf ^ 1, 1, cb + 32);
    buf ^= 1;
  }
  asm volatile("s_waitcnt vmcnt(0)" ::: "memory");  // drain LDS-DMA before exit

  // epilogue: gelu * wr, bf16 store
  bf16* hout = hbuf + ((size_t)pair * SR + m0 + wm * 128) * D_FF + n0 + wn * 64;
#pragma unroll
  for (int mi = 0; mi < 8; ++mi)
#pragma unroll
    for (int ni = 0; ni < 4; ++ni)
#pragma unroll
      for (int j = 0; j < 4; ++j) {
        float v = acc[mi][ni][j];
        hout[(size_t)(mi * 16 + fq * 4 + j) * D_FF + ni * 16 + fr] = (bf16)(gelu_tanh(v) * wr);
      }
}

// =====================================================================
// GEMM2 (unchanged from r5): 128x256 ring-3 pipelined, out = x + sum_r h @ Wb[e_r]
// =====================================================================

#define PSTAGE(slot_, kh_, SA_, SB_, sld_, scol_)                              \
  { const bf16* _sa = (SA_) + (size_t)(w * 16 + srow) * (sld_) + (scol_) + swz; \
    gload16(_sa, &As2[((slot_) * 2 + (kh_)) * 4096] + w * 512);                 \
    const bf16* _sb = (SB_) + (size_t)(w * 16 + srow) * (sld_) + (scol_) + swz; \
    gload16(_sb, &Bs2[((slot_) * 2 + (kh_)) * 8192] + w * 512);                 \
    gload16(_sb + (size_t)128 * (sld_), &Bs2[((slot_) * 2 + (kh_)) * 8192] + 4096 + w * 512); }

#define DSRD(AF_, BF_, slot_, kh_)                                             \
  { const bf16* Ah = &As2[((slot_) * 2 + (kh_)) * 4096] + (size_t)(wm * 64 + fr) * 32 + swr; \
    const bf16* Bh = &Bs2[((slot_) * 2 + (kh_)) * 8192] + (size_t)(wn * 64 + fr) * 32 + swr; \
    _Pragma("unroll")                                                          \
    for (int i = 0; i < 4; ++i) {                                              \
      AF_[i] = *(const bf16x8*)(Ah + i * 512);                                 \
      BF_[i] = *(const bf16x8*)(Bh + i * 512);                                 \
    } }

#define PHASE(curA, curB, nxtA, nxtB, rslot_, rkh_, sslot_, skh_, SA_, SB_, sld_, scb_) \
  { asm volatile("s_waitcnt vmcnt(6)" ::: "memory");                           \
    __builtin_amdgcn_s_barrier();                                              \
    __builtin_amdgcn_sched_barrier(0);                                         \
    DSRD(nxtA, nxtB, rslot_, rkh_);                                            \
    PSTAGE(sslot_, skh_, SA_, SB_, sld_, (scb_) + (skh_) * 32);                \
    asm volatile("s_waitcnt lgkmcnt(8)" ::: "memory");                         \
    __builtin_amdgcn_sched_barrier(0);                                         \
    __builtin_amdgcn_s_setprio(1);                                             \
    _Pragma("unroll")                                                          \
    for (int mi = 0; mi < 4; ++mi)                                             \
      _Pragma("unroll")                                                        \
      for (int ni = 0; ni < 4; ++ni)                                           \
        acc[mi][ni] = __builtin_amdgcn_mfma_f32_16x16x32_bf16(curA[mi], curB[ni], acc[mi][ni], 0, 0, 0); \
    __builtin_amdgcn_s_setprio(0); }

__launch_bounds__(512, 2)
__global__ void gemm2_kernel(const bf16* __restrict__ hbuf, const bf16* __restrict__ WbT,
                             const int* __restrict__ route_e,
                             const float* __restrict__ x, float* __restrict__ out,
                             int s_base, int SR) {
  __shared__ bf16 As2[3 * 2 * 4096];
  __shared__ bf16 Bs2[3 * 2 * 8192];
  int bx, by, bz;
  xcd_remap(bx, by, bz);
  const int b = bz;
  const int m0 = by * 128;
  const int n0 = bx * 256;
  const int tid = threadIdx.x;
  const int lane = tid & 63;
  const int w = tid >> 6;
  const int wm = w >> 2, wn = w & 3;
  const int fr = lane & 15, fq = lane >> 4;
  const int swz = (((lane & 3) ^ ((lane >> 3) & 3)) * 8);
  const int swr = ((fq ^ ((fr >> 1) & 3)) * 8);
  const int srow = lane >> 2;
  f32x4 acc[4][4] = {};
  bf16x8 afA[4], bfA[4], afB[4], bfB[4];

  const int e0 = route_e[b * TOPK + 0];
  const int e1 = route_e[b * TOPK + 1];
  const int e2 = route_e[b * TOPK + 2];
  const bf16* A0 = hbuf + ((size_t)(b * TOPK + 0) * SR + m0) * D_FF;
  const bf16* A1 = hbuf + ((size_t)(b * TOPK + 1) * SR + m0) * D_FF;
  const bf16* A2 = hbuf + ((size_t)(b * TOPK + 2) * SR + m0) * D_FF;
  const bf16* B0 = WbT + ((size_t)e0 * D_MODEL + n0) * D_FF;
  const bf16* B1 = WbT + ((size_t)e1 * D_MODEL + n0) * D_FF;
  const bf16* B2 = WbT + ((size_t)e2 * D_MODEL + n0) * D_FF;

  PSTAGE(0, 0, A0, B0, D_FF, 0);
  PSTAGE(0, 1, A0, B0, D_FF, 32);
  PSTAGE(1, 0, A0, B0, D_FF, 64);
  PSTAGE(1, 1, A0, B0, D_FF, 96);
  asm volatile("s_waitcnt vmcnt(9)" ::: "memory");
  __builtin_amdgcn_s_barrier();
  __builtin_amdgcn_sched_barrier(0);
  DSRD(afA, bfA, 0, 0);

  const int NT = TOPK * (D_FF / 64);  // 192, rank-major
  int sl = 0;
  for (int t = 0; t < NT; ++t) {
    int sp = sl + 2; if (sp >= 3) sp -= 3;
    int sln = sl + 1; if (sln >= 3) sln -= 3;
    const int tn = (t + 2 < NT) ? t + 2 : NT - 1;
    const int rn = tn >> 6;
    const bf16* SA = rn == 0 ? A0 : (rn == 1 ? A1 : A2);
    const bf16* SB = rn == 0 ? B0 : (rn == 1 ? B1 : B2);
    const int cb = (tn & 63) * 64;
    PHASE(afA, bfA, afB, bfB, sl, 1, sp, 0, SA, SB, D_FF, cb);
    PHASE(afB, bfB, afA, bfA, sln, 0, sp, 1, SA, SB, D_FF, cb);
    sl = sln;
  }
  asm volatile("s_waitcnt vmcnt(0)" ::: "memory");

  const size_t ob = ((size_t)b * SEQ + (size_t)(s_base + m0 + wm * 64)) * D_MODEL + n0 + wn * 64;
#pragma unroll
  for (int mi = 0; mi < 4; ++mi)
#pragma unroll
    for (int ni = 0; ni < 4; ++ni)
#pragma unroll
      for (int j = 0; j < 4; ++j) {
        size_t idx = ob + (size_t)(mi * 16 + fq * 4 + j) * D_MODEL + ni * 16 + fr;
        out[idx] = x[idx] + acc[mi][ni][j];
      }
}

// ---------------- sentinel ----------------

__global__ void fail_kernel(float* out, float v) {
  if (threadIdx.x < 64) out[threadIdx.x] = v;
}

// ---------------- host ----------------

extern "C" void kernel_launch(void* const* d_in, const int* in_sizes, int n_in,
                              void* d_out, int out_size, void* d_ws, size_t ws_size,
                              hipStream_t stream) {
  const float* x  = (const float*)d_in[0];
  const float* W1 = (const float*)d_in[1];
  const float* b1 = (const float*)d_in[2];
  const float* W2 = (const float*)d_in[3];
  const float* b2 = (const float*)d_in[4];
  const float* Wa = (const float*)d_in[5];
  const float* Wb = (const float*)d_in[6];
  float* out = (float*)d_out;

  char* ws = (char*)d_ws;
  size_t off = 0;
  auto walloc = [&](size_t bytes) -> void* {
    void* p = ws + off;
    off += (bytes + 255) & ~(size_t)255;
    return p;
  };

  float* partial = (float*)walloc((size_t)8 * BATCH * D_MODEL * 4);
  float* pooled  = (float*)walloc((size_t)BATCH * D_MODEL * 4);
  int*   route_e = (int*)walloc(NPAIR * 4);
  float* route_w = (float*)walloc(NPAIR * 4);
  int*   perm    = (int*)walloc(NPAIR * 4);
  bf16*  xb      = (bf16*)walloc((size_t)BATCH * SEQ * D_MODEL * 2);
  bf16*  WaT     = (bf16*)walloc((size_t)N_ZONES * D_MODEL * D_FF * 2);
  bf16*  WbT     = (bf16*)walloc((size_t)N_ZONES * D_MODEL * D_FF * 2);
  size_t fixed = off;

  int SR = 0;
  const int cands[2] = {512, 256};
  for (int ci = 0; ci < 2; ++ci) {
    size_t need = fixed + (size_t)NPAIR * cands[ci] * D_FF * 2 + 1024;
    if (need <= ws_size) { SR = cands[ci]; break; }
  }
  if (SR == 0) {
    fail_kernel<<<1, 64, 0, stream>>>(out, 1.0e6f + (float)(ws_size >> 20));
    return;
  }
  bf16* hbuf = (bf16*)walloc((size_t)NPAIR * SR * D_FF * 2);

  pool_partial_kernel<<<dim3(8, BATCH), 256, 0, stream>>>(x, partial);
  pool_final_kernel<<<BATCH, 256, 0, stream>>>(partial, pooled);
  router_kernel<<<BATCH, RH, 0, stream>>>(pooled, W1, b1, W2, b2, route_e, route_w);
  sort_pairs_kernel<<<1, 64, 0, stream>>>(route_e, perm);

  convert_x_kernel<<<(BATCH * SEQ * D_MODEL) / (256 * 8), 256, 0, stream>>>(x, xb);
  transpose_kernel<<<dim3(D_FF / 64, D_MODEL / 64, N_ZONES), 256, 0, stream>>>(Wa, WaT, D_MODEL, D_FF);
  transpose_kernel<<<dim3(D_MODEL / 64, D_FF / 64, N_ZONES), 256, 0, stream>>>(Wb, WbT, D_FF, D_MODEL);

  const int NS = SEQ / SR;
  for (int sl = 0; sl < NS; ++sl) {
    gemm1_kernel<<<dim3(D_FF / 256, SR / 256, NPAIR), 512, 0, stream>>>(
        xb, WaT, route_e, route_w, perm, hbuf, sl * SR, SR);
    gemm2_kernel<<<dim3(D_MODEL / 256, SR / 128, BATCH), 512, 0, stream>>>(
        hbuf, WbT, route_e, x, out, sl * SR, SR);
  }
}